// Round 6
// baseline (984.411 us; speedup 1.0000x reference)
//
#include <hip/hip_runtime.h>
#include <hip/hip_fp16.h>

typedef _Float16 f16;
typedef _Float16 f16x8 __attribute__((ext_vector_type(8)));
typedef __fp16 hf16x2 __attribute__((ext_vector_type(2)));
typedef float f32x4 __attribute__((ext_vector_type(4)));
typedef float f32x2 __attribute__((ext_vector_type(2)));
typedef unsigned int u32;
typedef u32 u32x4 __attribute__((ext_vector_type(4)));

#define HDIM 128
#define LAYERS 4
#define TS 32
#define NEG_BIG (-3.0e38f)

static __device__ __forceinline__ f32x4 mfma16(f16x8 a, f16x8 b, f32x4 c) {
  return __builtin_amdgcn_mfma_f32_16x16x32_f16(a, b, c, 0, 0, 0);
}

static __device__ __forceinline__ void atomicMaxF(float* addr, float val) {
  if (val >= 0.f) atomicMax((int*)addr, __float_as_int(val));
  else            atomicMin((unsigned int*)addr, __float_as_uint(val));
}

static __device__ __forceinline__ f16x8 pack4(hf16x2 a, hf16x2 b, hf16x2 c, hf16x2 d) {
  u32x4 u = {__builtin_bit_cast(u32, a), __builtin_bit_cast(u32, b),
             __builtin_bit_cast(u32, c), __builtin_bit_cast(u32, d)};
  return __builtin_bit_cast(f16x8, u);
}

// split two f32x4 into f16 hi/lo planes (packed converts, bit_cast packing)
static __device__ __forceinline__ void split8(f32x4 a, f32x4 b, f16x8& hv, f16x8& lv) {
  hf16x2 h0 = __builtin_amdgcn_cvt_pkrtz(a.x, a.y);
  hf16x2 h1 = __builtin_amdgcn_cvt_pkrtz(a.z, a.w);
  hf16x2 h2 = __builtin_amdgcn_cvt_pkrtz(b.x, b.y);
  hf16x2 h3 = __builtin_amdgcn_cvt_pkrtz(b.z, b.w);
  hv = pack4(h0, h1, h2, h3);
  hf16x2 l0 = __builtin_amdgcn_cvt_pkrtz(a.x - (float)h0[0], a.y - (float)h0[1]);
  hf16x2 l1 = __builtin_amdgcn_cvt_pkrtz(a.z - (float)h1[0], a.w - (float)h1[1]);
  hf16x2 l2 = __builtin_amdgcn_cvt_pkrtz(b.x - (float)h2[0], b.y - (float)h2[1]);
  hf16x2 l3 = __builtin_amdgcn_cvt_pkrtz(b.z - (float)h3[0], b.w - (float)h3[1]);
  lv = pack4(l0, l1, l2, l3);
}

// ---------------- CSR build (self-loops at slot 0 of each node) ----------------
__global__ void gnn_hist(const int* __restrict__ ei, int* __restrict__ deg, int E) {
  int e = blockIdx.x * 256 + threadIdx.x;
  if (e < E) atomicAdd(&deg[ei[E + e]], 1);
}

__global__ void gnn_bsum(const int* __restrict__ deg, int* __restrict__ bsum, int N) {
  __shared__ int red[256];
  int v = blockIdx.x * 256 + threadIdx.x;
  red[threadIdx.x] = (v < N) ? (deg[v] + 1) : 0;
  __syncthreads();
  for (int d = 128; d; d >>= 1) {
    if (threadIdx.x < d) red[threadIdx.x] += red[threadIdx.x + d];
    __syncthreads();
  }
  if (threadIdx.x == 0) bsum[blockIdx.x] = red[0];
}

__global__ void gnn_bscan(const int* __restrict__ bsum, int* __restrict__ boffs,
                          int* __restrict__ offs, int nb, int N) {
  __shared__ int sh[256];
  int t = threadIdx.x;
  sh[t] = (t < nb) ? bsum[t] : 0;
  __syncthreads();
  for (int d = 1; d < 256; d <<= 1) {
    int add = (t >= d) ? sh[t - d] : 0;
    __syncthreads();
    sh[t] += add;
    __syncthreads();
  }
  boffs[t] = (t > 0) ? sh[t - 1] : 0;
  if (t == 255) offs[N] = sh[255];
}

__global__ void gnn_scan_fin(const int* __restrict__ deg, const int* __restrict__ boffs,
                             int* __restrict__ offs, int* __restrict__ cursor,
                             int* __restrict__ colsrc, int* __restrict__ nodeof, int N) {
  __shared__ int sh[256];
  int t = threadIdx.x;
  int v = blockIdx.x * 256 + t;
  int val = (v < N) ? (deg[v] + 1) : 0;
  sh[t] = val;
  __syncthreads();
  for (int d = 1; d < 256; d <<= 1) {
    int add = (t >= d) ? sh[t - d] : 0;
    __syncthreads();
    sh[t] += add;
    __syncthreads();
  }
  if (v < N) {
    int excl = boffs[blockIdx.x] + sh[t] - val;
    offs[v] = excl;
    cursor[v] = excl + 1;       // slot 0 = self loop
    colsrc[excl] = v;
    int e = excl + val;
    for (int s = excl; s < e; s++) nodeof[s] = v;
  }
}

__global__ void gnn_scatter(const int* __restrict__ ei, int* __restrict__ cursor,
                            int* __restrict__ colsrc, int E) {
  int e = blockIdx.x * 256 + threadIdx.x;
  if (e < E) {
    int d = ei[E + e];
    int p = atomicAdd(&cursor[d], 1);
    colsrc[p] = ei[e];
  }
}

// ---------------- bias push-down precompute ----------------
__global__ void gnn_biasprep(const float* __restrict__ W1, const float* __restrict__ b1,
                             const float* __restrict__ b2, const float* __restrict__ Wf,
                             const float* __restrict__ bf, float* __restrict__ cbias,
                             float* __restrict__ bfp) {
  int l = blockIdx.x, c = threadIdx.x;
  if (l < LAYERS) {
    float s = 0.f;
    if (l > 0) {
      const float* bp = b2 + (size_t)(l - 1) * HDIM;
      if (c < 128) {
        for (int k = 0; k < 128; k++)
          s += bp[k] * (W1[((size_t)l * 256 + k) * 128 + c] - W1[((size_t)l * 256 + 128 + k) * 128 + c]);
      } else {
        int cc = c - 128;
        for (int k = 0; k < 128; k++)
          s += bp[k] * W1[((size_t)l * 256 + 128 + k) * 128 + cc];
      }
    }
    float base = (c < 128) ? b1[(size_t)l * HDIM + c] : 0.f;
    cbias[l * 256 + c] = base + s;
  } else if (c < 3) {
    float s = bf[c];
    for (int k = 0; k < 128; k++) s += b2[3 * HDIM + k] * Wf[k * 3 + c];
    bfp[c] = s;
  }
}

// ---------------- weight prep: fragment-ordered f16 hi/lo planes ----------------
__global__ void gnn_wprep1(const float* __restrict__ W1, f16* __restrict__ Wc) {
  int id = blockIdx.x * 256 + threadIdx.x;
  if (id >= LAYERS * 128 * 256) return;
  int col = id & 255, k = (id >> 8) & 127, l = id >> 15;
  float w;
  if (col < 128) w = W1[((size_t)l * 256 + k) * 128 + col] - W1[((size_t)l * 256 + 128 + k) * 128 + col];
  else           w = W1[((size_t)l * 256 + 128 + k) * 128 + (col - 128)];
  f16 hi = (f16)w;
  f16 lo = (f16)(w - (float)hi);
  int kk = k >> 5, quad = (k >> 3) & 3, j = k & 7;
  int ntile = col >> 4, lane = quad * 16 + (col & 15);
  size_t base = ((((size_t)l * 2 + 0) * 4 + kk) * 16 + ntile) * 512 + lane * 8 + j;
  Wc[base] = hi;
  Wc[base + (size_t)4 * 16 * 512] = lo;
}

__global__ void gnn_wprep2(const float* __restrict__ W2, f16* __restrict__ W2f) {
  int id = blockIdx.x * 256 + threadIdx.x;
  if (id >= LAYERS * 128 * 128) return;
  int n = id & 127, k = (id >> 7) & 127, l = id >> 14;
  float w = W2[((size_t)l * 128 + k) * 128 + n];
  f16 hi = (f16)w;
  f16 lo = (f16)(w - (float)hi);
  int kk = k >> 5, quad = (k >> 3) & 3, j = k & 7;
  int ntile = n >> 4, lane = quad * 16 + (n & 15);
  size_t base = ((((size_t)l * 2 + 0) * 4 + kk) * 8 + ntile) * 512 + lane * 8 + j;
  W2f[base] = hi;
  W2f[base + (size_t)4 * 8 * 512] = lo;
}

// ---------------- per-layer node GEMM: P = x@W1d + c1, Q = x@W1b + c2 ----------------
__global__ __launch_bounds__(256) void gnn_pq(const float* __restrict__ x,
    const f16* __restrict__ Wc, const float* __restrict__ cbias,
    float* __restrict__ P, float* __restrict__ Q, int N,
    const int* __restrict__ offs, int spb, float* __restrict__ xinit) {
  __shared__ __align__(16) f16 shA[2 * 4 * 4 * 64 * 8];
  int tid = threadIdx.x;
  int row0 = blockIdx.x * 64;
#pragma unroll
  for (int i = 0; i < 4; i++) {
    int p = i * 256 + tid;
    int row = p & 63, seg = p >> 6;
    f32x4 a = {}, b = {};
    int gr = row0 + row;
    if (gr < N) {
      const f32x4* xp = (const f32x4*)(x + (size_t)gr * HDIM + seg * 8);
      a = xp[0]; b = xp[1];
    }
    f16x8 hv, lv;
    split8(a, b, hv, lv);
    int kk = seg >> 2, quad = seg & 3, mt = row >> 4, m = row & 15;
    int lane = quad * 16 + m;
    int off = ((kk * 4 + mt) * 64 + lane) * 8;
    *(f16x8*)&shA[off] = hv;
    *(f16x8*)&shA[off + 4 * 4 * 64 * 8] = lv;
  }
  __syncthreads();
  int wave = tid >> 6, lane = tid & 63;
  int quad = lane >> 4, cl = lane & 15;
  f16x8 bw[2][4][4];
#pragma unroll
  for (int pl = 0; pl < 2; pl++)
#pragma unroll
    for (int nt = 0; nt < 4; nt++)
#pragma unroll
      for (int kk = 0; kk < 4; kk++) {
        int ntile = wave * 4 + nt;
        bw[pl][nt][kk] = *(const f16x8*)&Wc[(((size_t)(pl * 4 + kk) * 16 + ntile) * 64 + lane) * 8];
      }
#pragma unroll
  for (int mt = 0; mt < 4; mt++) {
    f32x4 acc[4] = {};
#pragma unroll
    for (int kk = 0; kk < 4; kk++) {
      f16x8 ah = *(const f16x8*)&shA[((kk * 4 + mt) * 64 + lane) * 8];
      f16x8 al = *(const f16x8*)&shA[(((4 + kk) * 4 + mt) * 64 + lane) * 8];
#pragma unroll
      for (int nt = 0; nt < 4; nt++) {
        acc[nt] = mfma16(ah, bw[0][nt][kk], acc[nt]);
        acc[nt] = mfma16(al, bw[0][nt][kk], acc[nt]);
        acc[nt] = mfma16(ah, bw[1][nt][kk], acc[nt]);
      }
    }
#pragma unroll
    for (int nt = 0; nt < 4; nt++) {
      int c = (wave * 4 + nt) * 16 + cl;
      float bb = cbias[c];
      float* dst = (c < HDIM) ? P : Q;
      int cc = c & 127;
#pragma unroll
      for (int i = 0; i < 4; i++) {
        int gr = row0 + mt * 16 + quad * 4 + i;
        if (gr < N) dst[(size_t)gr * HDIM + cc] = acc[nt][i] + bb;
      }
    }
  }
  // init straddler rows of xinit to NEG_BIG (rare: ~2% of nodes)
  if (tid < 64) {
    int v = row0 + tid;
    if (v < N) {
      int a = offs[v], b = offs[v + 1] - 1;
      if (a / spb != b / spb) {
        f32x4 ninf = {NEG_BIG, NEG_BIG, NEG_BIG, NEG_BIG};
        float* xr = xinit + (size_t)v * HDIM;
#pragma unroll
        for (int c = 0; c < HDIM; c += 4) *(f32x4*)(xr + c) = ninf;
      }
    }
  }
}

// ---------------- persistent slot-tile edge MLP + segmented max ----------------
// block owns slots [blk0, blk1), loops 32-slot tiles with a 2-level prefetch
// pipeline: idx 2 tiles ahead, gather data 1 tile ahead (issued after B1 so
// the loads fly during the GEMM and drain at B2).
__global__ __launch_bounds__(256, 4) void gnn_edge5(
    const float* __restrict__ P, const float* __restrict__ Q,
    const int* __restrict__ offs, const int* __restrict__ colsrc,
    const int* __restrict__ nodeof, const f16* __restrict__ W2f,
    float* __restrict__ xout, int S, int spb) {
  __shared__ __align__(16) f16 shA[2 * 4 * 2 * 64 * 8];   // 16384 B
  __shared__ __align__(16) float msg[TS * 132];            // 16896 B
  __shared__ __align__(16) float stradV[2][128];
  __shared__ int stradN[2];
  int tid = threadIdx.x;
  int wave = tid >> 6, lane = tid & 63;
  int quad = lane >> 4, cl = lane & 15;
  f16x8 bw[2][2][4];
#pragma unroll
  for (int pl = 0; pl < 2; pl++)
#pragma unroll
    for (int nt = 0; nt < 2; nt++)
#pragma unroll
      for (int kk = 0; kk < 4; kk++)
        bw[pl][nt][kk] = *(const f16x8*)&W2f[(((size_t)(pl * 4 + kk) * 8 + (wave * 2 + nt)) * 64 + lane) * 8];
  int blk0 = blockIdx.x * spb;
  int blk1 = blk0 + spb; if (blk1 > S) blk1 = S;
  if (tid < 2) stradN[tid] = -1;
  int sl = tid >> 4, seg = tid & 15;       // 16 lanes cover one slot's 512B row
  int kkb = seg >> 2, qb = seg & 3;
  int laneF = qb * 16 + sl;
  int Sm1 = S - 1;

  int cs[2], nd[2];          // indices for the NEXT tile's data loads
  f32x4 qv[2][2], pv[2][2];  // gather data for the CURRENT tile
  // prologue: idx(t0) -> data(t0) -> idx(t1)
#pragma unroll
  for (int i = 0; i < 2; i++) {
    int slc = blk0 + i * 16 + sl; slc = (slc < S) ? slc : Sm1;
    cs[i] = colsrc[slc]; nd[i] = nodeof[slc];
  }
#pragma unroll
  for (int i = 0; i < 2; i++) {
    const f32x4* qp = (const f32x4*)(Q + (size_t)cs[i] * HDIM + seg * 8);
    const f32x4* pp = (const f32x4*)(P + (size_t)nd[i] * HDIM + seg * 8);
    qv[i][0] = qp[0]; qv[i][1] = qp[1];
    pv[i][0] = pp[0]; pv[i][1] = pp[1];
  }
#pragma unroll
  for (int i = 0; i < 2; i++) {
    int slc = blk0 + TS + i * 16 + sl; slc = (slc < S) ? slc : Sm1;
    cs[i] = colsrc[slc]; nd[i] = nodeof[slc];
  }

  int tc = 0;
  for (int t0 = blk0; t0 < blk1; t0 += TS, tc++) {
    int par = tc & 1, prv = par ^ 1;
    int tEnd = t0 + TS; if (tEnd > blk1) tEnd = blk1;
    // ---- build shA from prefetched qv/pv ----
#pragma unroll
    for (int i = 0; i < 2; i++) {
      f32x4 sa, sb;
      sa.x = fmaxf(pv[i][0].x + qv[i][0].x, 0.f); sa.y = fmaxf(pv[i][0].y + qv[i][0].y, 0.f);
      sa.z = fmaxf(pv[i][0].z + qv[i][0].z, 0.f); sa.w = fmaxf(pv[i][0].w + qv[i][0].w, 0.f);
      sb.x = fmaxf(pv[i][1].x + qv[i][1].x, 0.f); sb.y = fmaxf(pv[i][1].y + qv[i][1].y, 0.f);
      sb.z = fmaxf(pv[i][1].z + qv[i][1].z, 0.f); sb.w = fmaxf(pv[i][1].w + qv[i][1].w, 0.f);
      f16x8 hv, lv;
      split8(sa, sb, hv, lv);
      int off = ((kkb * 2 + i) * 64 + laneF) * 8;
      *(f16x8*)&shA[off] = hv;
      *(f16x8*)&shA[off + 4096] = lv;      // lo plane
    }
    __syncthreads();                       // B1: shA complete
    if (tid == 0) stradN[par] = -1;
    // ---- prefetch: data for t+1 (idx already resident), idx for t+2 ----
    if (t0 + TS < blk1) {
#pragma unroll
      for (int i = 0; i < 2; i++) {
        const f32x4* qp = (const f32x4*)(Q + (size_t)cs[i] * HDIM + seg * 8);
        const f32x4* pp = (const f32x4*)(P + (size_t)nd[i] * HDIM + seg * 8);
        qv[i][0] = qp[0]; qv[i][1] = qp[1];
        pv[i][0] = pp[0]; pv[i][1] = pp[1];
      }
#pragma unroll
      for (int i = 0; i < 2; i++) {
        int slc = t0 + 2 * TS + i * 16 + sl; slc = (slc < S) ? slc : Sm1;
        cs[i] = colsrc[slc]; nd[i] = nodeof[slc];
      }
    }
    // ---- GEMM: wave covers cols [wave*32, wave*32+32) ----
    f32x4 acc[2][2] = {};
#pragma unroll
    for (int kk = 0; kk < 4; kk++)
#pragma unroll
      for (int mt = 0; mt < 2; mt++) {
        int off = ((kk * 2 + mt) * 64 + lane) * 8;
        f16x8 ah = *(const f16x8*)&shA[off];
        f16x8 al = *(const f16x8*)&shA[off + 4096];
#pragma unroll
        for (int nt = 0; nt < 2; nt++) {
          acc[mt][nt] = mfma16(ah, bw[0][nt][kk], acc[mt][nt]);
          acc[mt][nt] = mfma16(al, bw[0][nt][kk], acc[mt][nt]);
          acc[mt][nt] = mfma16(ah, bw[1][nt][kk], acc[mt][nt]);
        }
      }
    // ---- C -> msg (row-major, 2-way-free banks) ----
#pragma unroll
    for (int mt = 0; mt < 2; mt++)
#pragma unroll
      for (int nt = 0; nt < 2; nt++) {
        int col = wave * 32 + nt * 16 + cl;
#pragma unroll
        for (int i = 0; i < 4; i++) {
          int row = mt * 16 + quad * 4 + i;
          msg[row * 132 + col] = acc[mt][nt][i];
        }
      }
    __syncthreads();                       // B2: msg complete, prefetch drained
    // ---- col4 segmented max ----
    int vA = nodeof[t0];
    int vB = nodeof[tEnd - 1];
    int sNp = stradN[prv];
    int ngroups = (vB - vA + 1) << 5;      // nodes × 32 col4-groups
    for (int p = tid; p < ngroups; p += 256) {
      int v = vA + (p >> 5), c4 = (p & 31) << 2;
      int a = offs[v], b = offs[v + 1];
      int r0 = (a > t0 ? a : t0) - t0;
      int r1 = (b < tEnd ? b : tEnd) - t0;
      f32x4 m = {NEG_BIG, NEG_BIG, NEG_BIG, NEG_BIG};
      for (int r = r0; r < r1; r++) {
        f32x4 x = *(const f32x4*)&msg[r * 132 + c4];
        m.x = fmaxf(m.x, x.x); m.y = fmaxf(m.y, x.y);
        m.z = fmaxf(m.z, x.z); m.w = fmaxf(m.w, x.w);
      }
      if (v == sNp) {
        f32x4 sv = *(const f32x4*)&stradV[prv][c4];
        m.x = fmaxf(m.x, sv.x); m.y = fmaxf(m.y, sv.y);
        m.z = fmaxf(m.z, sv.z); m.w = fmaxf(m.w, sv.w);
      }
      if (b > tEnd && tEnd < blk1) {
        *(f32x4*)&stradV[par][c4] = m;     // carry to next tile (only vB qualifies)
        if ((p & 31) == 0) stradN[par] = v;
      } else {
        float* dp = &xout[(size_t)v * HDIM + c4];
        if (a < blk0 || b > blk1) {
          atomicMaxF(dp + 0, m.x); atomicMaxF(dp + 1, m.y);
          atomicMaxF(dp + 2, m.z); atomicMaxF(dp + 3, m.w);
        } else {
          *(f32x4*)dp = m;
        }
      }
    }
    // next tile's B1 protects shA; B2 protects msg/strad
  }
}

// ---------------- final fc: out = x @ Wf + bfp ----------------
__global__ __launch_bounds__(256) void gnn_fc(const float* __restrict__ x,
    const float* __restrict__ Wf, const float* __restrict__ bfp,
    float* __restrict__ out, int N) {
  int wave = threadIdx.x >> 6, lane = threadIdx.x & 63;
  int wid = blockIdx.x * 4 + wave, nw = gridDim.x * 4;
  int k0 = lane * 2;
  float w00 = Wf[k0 * 3 + 0], w01 = Wf[k0 * 3 + 1], w02 = Wf[k0 * 3 + 2];
  float w10 = Wf[k0 * 3 + 3], w11 = Wf[k0 * 3 + 4], w12 = Wf[k0 * 3 + 5];
  float bf0 = bfp[0], bf1 = bfp[1], bf2 = bfp[2];
  for (int v = wid; v < N; v += nw) {
    f32x2 xx = *(const f32x2*)(x + (size_t)v * HDIM + k0);
    float d0 = xx.x * w00 + xx.y * w10;
    float d1 = xx.x * w01 + xx.y * w11;
    float d2 = xx.x * w02 + xx.y * w12;
#pragma unroll
    for (int s = 32; s; s >>= 1) {
      d0 += __shfl_xor(d0, s, 64);
      d1 += __shfl_xor(d1, s, 64);
      d2 += __shfl_xor(d2, s, 64);
    }
    if (lane == 0) {
      out[(size_t)v * 3 + 0] = d0 + bf0;
      out[(size_t)v * 3 + 1] = d1 + bf1;
      out[(size_t)v * 3 + 2] = d2 + bf2;
    }
  }
}

extern "C" void kernel_launch(void* const* d_in, const int* in_sizes, int n_in,
                              void* d_out, int out_size, void* d_ws, size_t ws_size,
                              hipStream_t stream) {
  const float* x_in = (const float*)d_in[0];
  const int*   ei   = (const int*)d_in[1];
  const float* W1   = (const float*)d_in[2];
  const float* b1   = (const float*)d_in[3];
  const float* W2   = (const float*)d_in[4];
  const float* b2   = (const float*)d_in[5];
  const float* Wf   = (const float*)d_in[6];
  const float* bfv  = (const float*)d_in[7];
  float* outp = (float*)d_out;
  int N = in_sizes[0] / HDIM;
  int E = in_sizes[1] / 2;
  int S = E + N;

  char* ws = (char*)d_ws;
  size_t o = 0;
  auto alloc = [&](size_t bytes) -> char* {
    char* p = ws + o;
    o += (bytes + 255) & ~(size_t)255;
    return p;
  };
  int*   deg    = (int*)alloc((size_t)N * 4);
  int*   offs   = (int*)alloc(((size_t)N + 1) * 4);
  int*   cursor = (int*)alloc((size_t)N * 4);
  int*   colsrc = (int*)alloc((size_t)S * 4);
  int*   nodeof = (int*)alloc((size_t)S * 4);
  int*   bsum   = (int*)alloc(256 * 4);
  int*   boffs  = (int*)alloc(256 * 4);
  float* cbias  = (float*)alloc((size_t)LAYERS * 256 * 4);
  float* bfp    = (float*)alloc(4 * 4);
  float* P      = (float*)alloc((size_t)N * HDIM * 4);
  float* Q      = (float*)alloc((size_t)N * HDIM * 4);
  float* xbuf   = (float*)alloc((size_t)N * HDIM * 4);
  f16*   Wc     = (f16*)alloc((size_t)LAYERS * 65536 * 2);
  f16*   W2f    = (f16*)alloc((size_t)LAYERS * 32768 * 2);
  (void)ws_size; (void)n_in; (void)out_size;

  int nb = (N + 255) / 256;
  hipMemsetAsync(deg, 0, (size_t)N * 4, stream);
  gnn_hist<<<(E + 255) / 256, 256, 0, stream>>>(ei, deg, E);
  gnn_bsum<<<nb, 256, 0, stream>>>(deg, bsum, N);
  gnn_bscan<<<1, 256, 0, stream>>>(bsum, boffs, offs, nb, N);
  gnn_scan_fin<<<nb, 256, 0, stream>>>(deg, boffs, offs, cursor, colsrc, nodeof, N);
  gnn_scatter<<<(E + 255) / 256, 256, 0, stream>>>(ei, cursor, colsrc, E);
  gnn_biasprep<<<LAYERS + 1, 256, 0, stream>>>(W1, b1, b2, Wf, bfv, cbias, bfp);
  gnn_wprep1<<<(LAYERS * 128 * 256 + 255) / 256, 256, 0, stream>>>(W1, Wc);
  gnn_wprep2<<<(LAYERS * 128 * 128 + 255) / 256, 256, 0, stream>>>(W2, W2f);

  // slots per block: ~S/1024, rounded up to a multiple of TS(32)
  int spb = ((((S + 1023) / 1024) + TS - 1) / TS) * TS;
  int NB = (S + spb - 1) / spb;
  const float* xc = x_in;
  for (int l = 0; l < LAYERS; l++) {
    gnn_pq<<<(N + 63) / 64, 256, 0, stream>>>(xc, Wc + (size_t)l * 65536, cbias + l * 256,
                                              P, Q, N, offs, spb, xbuf);
    gnn_edge5<<<NB, 256, 0, stream>>>(P, Q, offs, colsrc, nodeof, W2f + (size_t)l * 32768,
                                      xbuf, S, spb);
    xc = xbuf;
  }
  gnn_fc<<<256, 256, 0, stream>>>(xc, Wf, bfp, outp, N);
}

// Round 7
// 830.787 us; speedup vs baseline: 1.1849x; 1.1849x over previous
//
#include <hip/hip_runtime.h>
#include <hip/hip_fp16.h>

typedef _Float16 f16;
typedef _Float16 f16x8 __attribute__((ext_vector_type(8)));
typedef __fp16 hf16x2 __attribute__((ext_vector_type(2)));
typedef float f32x4 __attribute__((ext_vector_type(4)));
typedef float f32x2 __attribute__((ext_vector_type(2)));
typedef unsigned int u32;
typedef u32 u32x4 __attribute__((ext_vector_type(4)));

#define HDIM 128
#define LAYERS 4
#define TS 32
#define NEG_BIG (-3.0e38f)

static __device__ __forceinline__ f32x4 mfma16(f16x8 a, f16x8 b, f32x4 c) {
  return __builtin_amdgcn_mfma_f32_16x16x32_f16(a, b, c, 0, 0, 0);
}

static __device__ __forceinline__ void atomicMaxF(float* addr, float val) {
  if (val >= 0.f) atomicMax((int*)addr, __float_as_int(val));
  else            atomicMin((unsigned int*)addr, __float_as_uint(val));
}

static __device__ __forceinline__ f16x8 pack4(hf16x2 a, hf16x2 b, hf16x2 c, hf16x2 d) {
  u32x4 u = {__builtin_bit_cast(u32, a), __builtin_bit_cast(u32, b),
             __builtin_bit_cast(u32, c), __builtin_bit_cast(u32, d)};
  return __builtin_bit_cast(f16x8, u);
}

// split two f32x4 into f16 hi/lo planes (packed converts, bit_cast packing)
static __device__ __forceinline__ void split8(f32x4 a, f32x4 b, f16x8& hv, f16x8& lv) {
  hf16x2 h0 = __builtin_amdgcn_cvt_pkrtz(a.x, a.y);
  hf16x2 h1 = __builtin_amdgcn_cvt_pkrtz(a.z, a.w);
  hf16x2 h2 = __builtin_amdgcn_cvt_pkrtz(b.x, b.y);
  hf16x2 h3 = __builtin_amdgcn_cvt_pkrtz(b.z, b.w);
  hv = pack4(h0, h1, h2, h3);
  hf16x2 l0 = __builtin_amdgcn_cvt_pkrtz(a.x - (float)h0[0], a.y - (float)h0[1]);
  hf16x2 l1 = __builtin_amdgcn_cvt_pkrtz(a.z - (float)h1[0], a.w - (float)h1[1]);
  hf16x2 l2 = __builtin_amdgcn_cvt_pkrtz(b.x - (float)h2[0], b.y - (float)h2[1]);
  hf16x2 l3 = __builtin_amdgcn_cvt_pkrtz(b.z - (float)h3[0], b.w - (float)h3[1]);
  lv = pack4(l0, l1, l2, l3);
}

// ---------------- CSR build (self-loops at slot 0 of each node) ----------------
__global__ void gnn_hist(const int* __restrict__ ei, int* __restrict__ deg, int E) {
  int e = blockIdx.x * 256 + threadIdx.x;
  if (e < E) atomicAdd(&deg[ei[E + e]], 1);
}

__global__ void gnn_bsum(const int* __restrict__ deg, int* __restrict__ bsum, int N) {
  __shared__ int red[256];
  int v = blockIdx.x * 256 + threadIdx.x;
  red[threadIdx.x] = (v < N) ? (deg[v] + 1) : 0;
  __syncthreads();
  for (int d = 128; d; d >>= 1) {
    if (threadIdx.x < d) red[threadIdx.x] += red[threadIdx.x + d];
    __syncthreads();
  }
  if (threadIdx.x == 0) bsum[blockIdx.x] = red[0];
}

__global__ void gnn_bscan(const int* __restrict__ bsum, int* __restrict__ boffs,
                          int* __restrict__ offs, int nb, int N) {
  __shared__ int sh[256];
  int t = threadIdx.x;
  sh[t] = (t < nb) ? bsum[t] : 0;
  __syncthreads();
  for (int d = 1; d < 256; d <<= 1) {
    int add = (t >= d) ? sh[t - d] : 0;
    __syncthreads();
    sh[t] += add;
    __syncthreads();
  }
  boffs[t] = (t > 0) ? sh[t - 1] : 0;
  if (t == 255) offs[N] = sh[255];
}

__global__ void gnn_scan_fin(const int* __restrict__ deg, const int* __restrict__ boffs,
                             int* __restrict__ offs, int* __restrict__ cursor,
                             int* __restrict__ colsrc, int* __restrict__ nodeof, int N) {
  __shared__ int sh[256];
  int t = threadIdx.x;
  int v = blockIdx.x * 256 + t;
  int val = (v < N) ? (deg[v] + 1) : 0;
  sh[t] = val;
  __syncthreads();
  for (int d = 1; d < 256; d <<= 1) {
    int add = (t >= d) ? sh[t - d] : 0;
    __syncthreads();
    sh[t] += add;
    __syncthreads();
  }
  if (v < N) {
    int excl = boffs[blockIdx.x] + sh[t] - val;
    offs[v] = excl;
    cursor[v] = excl + 1;       // slot 0 = self loop
    colsrc[excl] = v;
    int e = excl + val;
    for (int s = excl; s < e; s++) nodeof[s] = v;
  }
}

__global__ void gnn_scatter(const int* __restrict__ ei, int* __restrict__ cursor,
                            int* __restrict__ colsrc, int E) {
  int e = blockIdx.x * 256 + threadIdx.x;
  if (e < E) {
    int d = ei[E + e];
    int p = atomicAdd(&cursor[d], 1);
    colsrc[p] = ei[e];
  }
}

// ---------------- bias push-down precompute ----------------
__global__ void gnn_biasprep(const float* __restrict__ W1, const float* __restrict__ b1,
                             const float* __restrict__ b2, const float* __restrict__ Wf,
                             const float* __restrict__ bf, float* __restrict__ cbias,
                             float* __restrict__ bfp) {
  int l = blockIdx.x, c = threadIdx.x;
  if (l < LAYERS) {
    float s = 0.f;
    if (l > 0) {
      const float* bp = b2 + (size_t)(l - 1) * HDIM;
      if (c < 128) {
        for (int k = 0; k < 128; k++)
          s += bp[k] * (W1[((size_t)l * 256 + k) * 128 + c] - W1[((size_t)l * 256 + 128 + k) * 128 + c]);
      } else {
        int cc = c - 128;
        for (int k = 0; k < 128; k++)
          s += bp[k] * W1[((size_t)l * 256 + 128 + k) * 128 + cc];
      }
    }
    float base = (c < 128) ? b1[(size_t)l * HDIM + c] : 0.f;
    cbias[l * 256 + c] = base + s;
  } else if (c < 3) {
    float s = bf[c];
    for (int k = 0; k < 128; k++) s += b2[3 * HDIM + k] * Wf[k * 3 + c];
    bfp[c] = s;
  }
}

// ---------------- weight prep: fragment-ordered f16 hi/lo planes ----------------
__global__ void gnn_wprep1(const float* __restrict__ W1, f16* __restrict__ Wc) {
  int id = blockIdx.x * 256 + threadIdx.x;
  if (id >= LAYERS * 128 * 256) return;
  int col = id & 255, k = (id >> 8) & 127, l = id >> 15;
  float w;
  if (col < 128) w = W1[((size_t)l * 256 + k) * 128 + col] - W1[((size_t)l * 256 + 128 + k) * 128 + col];
  else           w = W1[((size_t)l * 256 + 128 + k) * 128 + (col - 128)];
  f16 hi = (f16)w;
  f16 lo = (f16)(w - (float)hi);
  int kk = k >> 5, quad = (k >> 3) & 3, j = k & 7;
  int ntile = col >> 4, lane = quad * 16 + (col & 15);
  size_t base = ((((size_t)l * 2 + 0) * 4 + kk) * 16 + ntile) * 512 + lane * 8 + j;
  Wc[base] = hi;
  Wc[base + (size_t)4 * 16 * 512] = lo;
}

__global__ void gnn_wprep2(const float* __restrict__ W2, f16* __restrict__ W2f) {
  int id = blockIdx.x * 256 + threadIdx.x;
  if (id >= LAYERS * 128 * 128) return;
  int n = id & 127, k = (id >> 7) & 127, l = id >> 14;
  float w = W2[((size_t)l * 128 + k) * 128 + n];
  f16 hi = (f16)w;
  f16 lo = (f16)(w - (float)hi);
  int kk = k >> 5, quad = (k >> 3) & 3, j = k & 7;
  int ntile = n >> 4, lane = quad * 16 + (n & 15);
  size_t base = ((((size_t)l * 2 + 0) * 4 + kk) * 8 + ntile) * 512 + lane * 8 + j;
  W2f[base] = hi;
  W2f[base + (size_t)4 * 8 * 512] = lo;
}

// ---------------- per-layer node GEMM: P = x@W1d + c1, Q = x@W1b + c2 ----------------
__global__ __launch_bounds__(256) void gnn_pq(const float* __restrict__ x,
    const f16* __restrict__ Wc, const float* __restrict__ cbias,
    float* __restrict__ P, float* __restrict__ Q, int N,
    const int* __restrict__ offs, int spb, float* __restrict__ xinit) {
  __shared__ __align__(16) f16 shA[2 * 4 * 4 * 64 * 8];
  int tid = threadIdx.x;
  int row0 = blockIdx.x * 64;
#pragma unroll
  for (int i = 0; i < 4; i++) {
    int p = i * 256 + tid;
    int row = p & 63, seg = p >> 6;
    f32x4 a = {}, b = {};
    int gr = row0 + row;
    if (gr < N) {
      const f32x4* xp = (const f32x4*)(x + (size_t)gr * HDIM + seg * 8);
      a = xp[0]; b = xp[1];
    }
    f16x8 hv, lv;
    split8(a, b, hv, lv);
    int kk = seg >> 2, quad = seg & 3, mt = row >> 4, m = row & 15;
    int lane = quad * 16 + m;
    int off = ((kk * 4 + mt) * 64 + lane) * 8;
    *(f16x8*)&shA[off] = hv;
    *(f16x8*)&shA[off + 4 * 4 * 64 * 8] = lv;
  }
  __syncthreads();
  int wave = tid >> 6, lane = tid & 63;
  int quad = lane >> 4, cl = lane & 15;
  f16x8 bw[2][4][4];
#pragma unroll
  for (int pl = 0; pl < 2; pl++)
#pragma unroll
    for (int nt = 0; nt < 4; nt++)
#pragma unroll
      for (int kk = 0; kk < 4; kk++) {
        int ntile = wave * 4 + nt;
        bw[pl][nt][kk] = *(const f16x8*)&Wc[(((size_t)(pl * 4 + kk) * 16 + ntile) * 64 + lane) * 8];
      }
#pragma unroll
  for (int mt = 0; mt < 4; mt++) {
    f32x4 acc[4] = {};
#pragma unroll
    for (int kk = 0; kk < 4; kk++) {
      f16x8 ah = *(const f16x8*)&shA[((kk * 4 + mt) * 64 + lane) * 8];
      f16x8 al = *(const f16x8*)&shA[(((4 + kk) * 4 + mt) * 64 + lane) * 8];
#pragma unroll
      for (int nt = 0; nt < 4; nt++) {
        acc[nt] = mfma16(ah, bw[0][nt][kk], acc[nt]);
        acc[nt] = mfma16(al, bw[0][nt][kk], acc[nt]);
        acc[nt] = mfma16(ah, bw[1][nt][kk], acc[nt]);
      }
    }
#pragma unroll
    for (int nt = 0; nt < 4; nt++) {
      int c = (wave * 4 + nt) * 16 + cl;
      float bb = cbias[c];
      float* dst = (c < HDIM) ? P : Q;
      int cc = c & 127;
#pragma unroll
      for (int i = 0; i < 4; i++) {
        int gr = row0 + mt * 16 + quad * 4 + i;
        if (gr < N) dst[(size_t)gr * HDIM + cc] = acc[nt][i] + bb;
      }
    }
  }
  // init straddler rows of xinit to NEG_BIG (rare: ~2% of nodes)
  if (tid < 64) {
    int v = row0 + tid;
    if (v < N) {
      int a = offs[v], b = offs[v + 1] - 1;
      if (a / spb != b / spb) {
        f32x4 ninf = {NEG_BIG, NEG_BIG, NEG_BIG, NEG_BIG};
        float* xr = xinit + (size_t)v * HDIM;
#pragma unroll
        for (int c = 0; c < HDIM; c += 4) *(f32x4*)(xr + c) = ninf;
      }
    }
  }
}

// ---------------- persistent slot-tile edge MLP + segmented max ----------------
// block owns slots [blk0, blk1), loops 32-slot tiles. build -> B1 -> GEMM+Cwrite ->
// B2 -> col4 segmented max with LDS carry chain; block-boundary nodes via atomicMaxF.
// No register data prefetch (R6 showed it spills at the 4-block VGPR budget).
__global__ __launch_bounds__(256, 4) void gnn_edge6(
    const float* __restrict__ P, const float* __restrict__ Q,
    const int* __restrict__ offs, const int* __restrict__ colsrc,
    const int* __restrict__ nodeof, const f16* __restrict__ W2f,
    float* __restrict__ xout, int S, int spb) {
  __shared__ __align__(16) f16 shA[2 * 4 * 2 * 64 * 8];   // 16384 B
  __shared__ __align__(16) float msg[TS * 132];            // 16896 B
  __shared__ __align__(16) float stradV[2][128];
  __shared__ int stradN[2];
  int tid = threadIdx.x;
  int wave = tid >> 6, lane = tid & 63;
  int quad = lane >> 4, cl = lane & 15;
  f16x8 bw[2][2][4];
#pragma unroll
  for (int pl = 0; pl < 2; pl++)
#pragma unroll
    for (int nt = 0; nt < 2; nt++)
#pragma unroll
      for (int kk = 0; kk < 4; kk++)
        bw[pl][nt][kk] = *(const f16x8*)&W2f[(((size_t)(pl * 4 + kk) * 8 + (wave * 2 + nt)) * 64 + lane) * 8];
  int blk0 = blockIdx.x * spb;
  int blk1 = blk0 + spb; if (blk1 > S) blk1 = S;
  if (tid < 2) stradN[tid] = -1;
  int sl = tid >> 4, seg = tid & 15;       // 16 lanes cover one slot's 512B row
  int kkb = seg >> 2, qb = seg & 3;
  int laneF = qb * 16 + sl;
  int Sm1 = S - 1;
  int tc = 0;
  for (int t0 = blk0; t0 < blk1; t0 += TS, tc++) {
    int par = tc & 1, prv = par ^ 1;
    int tEnd = t0 + TS; if (tEnd > blk1) tEnd = blk1;
    // ---- build: 16 consecutive lanes cover one slot's 512B row (coalesced) ----
#pragma unroll
    for (int i = 0; i < 2; i++) {
      int slot = t0 + i * 16 + sl;
      int slc = (slot < S) ? slot : Sm1;
      int src = colsrc[slc];
      int dst = nodeof[slc];
      const f32x4* qp = (const f32x4*)(Q + (size_t)src * HDIM + seg * 8);
      const f32x4* pp = (const f32x4*)(P + (size_t)dst * HDIM + seg * 8);
      f32x4 qa = qp[0], qb4 = qp[1], pa = pp[0], pb = pp[1];
      f32x4 sa, sb;
      sa.x = fmaxf(pa.x + qa.x, 0.f); sa.y = fmaxf(pa.y + qa.y, 0.f);
      sa.z = fmaxf(pa.z + qa.z, 0.f); sa.w = fmaxf(pa.w + qa.w, 0.f);
      sb.x = fmaxf(pb.x + qb4.x, 0.f); sb.y = fmaxf(pb.y + qb4.y, 0.f);
      sb.z = fmaxf(pb.z + qb4.z, 0.f); sb.w = fmaxf(pb.w + qb4.w, 0.f);
      f16x8 hv, lv;
      split8(sa, sb, hv, lv);
      int off = ((kkb * 2 + i) * 64 + laneF) * 8;
      *(f16x8*)&shA[off] = hv;
      *(f16x8*)&shA[off + 4096] = lv;      // lo plane
    }
    __syncthreads();                       // B1: shA complete
    if (tid == 0) stradN[par] = -1;
    // ---- GEMM: wave covers cols [wave*32, wave*32+32) ----
    f32x4 acc[2][2] = {};
#pragma unroll
    for (int kk = 0; kk < 4; kk++)
#pragma unroll
      for (int mt = 0; mt < 2; mt++) {
        int off = ((kk * 2 + mt) * 64 + lane) * 8;
        f16x8 ah = *(const f16x8*)&shA[off];
        f16x8 al = *(const f16x8*)&shA[off + 4096];
#pragma unroll
        for (int nt = 0; nt < 2; nt++) {
          acc[mt][nt] = mfma16(ah, bw[0][nt][kk], acc[mt][nt]);
          acc[mt][nt] = mfma16(al, bw[0][nt][kk], acc[mt][nt]);
          acc[mt][nt] = mfma16(ah, bw[1][nt][kk], acc[mt][nt]);
        }
      }
    // ---- C -> msg (row-major, 2-way-free banks) ----
#pragma unroll
    for (int mt = 0; mt < 2; mt++)
#pragma unroll
      for (int nt = 0; nt < 2; nt++) {
        int col = wave * 32 + nt * 16 + cl;
#pragma unroll
        for (int i = 0; i < 4; i++) {
          int row = mt * 16 + quad * 4 + i;
          msg[row * 132 + col] = acc[mt][nt][i];
        }
      }
    __syncthreads();                       // B2: msg complete
    // ---- col4 segmented max ----
    int vA = nodeof[t0];
    int vB = nodeof[tEnd - 1];
    int sNp = stradN[prv];
    int ngroups = (vB - vA + 1) << 5;      // nodes × 32 col4-groups
    for (int p = tid; p < ngroups; p += 256) {
      int v = vA + (p >> 5), c4 = (p & 31) << 2;
      int a = offs[v], b = offs[v + 1];
      int r0 = (a > t0 ? a : t0) - t0;
      int r1 = (b < tEnd ? b : tEnd) - t0;
      f32x4 m = {NEG_BIG, NEG_BIG, NEG_BIG, NEG_BIG};
      for (int r = r0; r < r1; r++) {
        f32x4 x = *(const f32x4*)&msg[r * 132 + c4];
        m.x = fmaxf(m.x, x.x); m.y = fmaxf(m.y, x.y);
        m.z = fmaxf(m.z, x.z); m.w = fmaxf(m.w, x.w);
      }
      if (v == sNp) {
        f32x4 sv = *(const f32x4*)&stradV[prv][c4];
        m.x = fmaxf(m.x, sv.x); m.y = fmaxf(m.y, sv.y);
        m.z = fmaxf(m.z, sv.z); m.w = fmaxf(m.w, sv.w);
      }
      if (b > tEnd && tEnd < blk1) {
        *(f32x4*)&stradV[par][c4] = m;     // carry to next tile (only vB qualifies)
        if ((p & 31) == 0) stradN[par] = v;
      } else {
        float* dp = &xout[(size_t)v * HDIM + c4];
        if (a < blk0 || b > blk1) {
          atomicMaxF(dp + 0, m.x); atomicMaxF(dp + 1, m.y);
          atomicMaxF(dp + 2, m.z); atomicMaxF(dp + 3, m.w);
        } else {
          *(f32x4*)dp = m;
        }
      }
    }
    // next tile's B1 protects shA; B2 protects msg/strad
  }
}

// ---------------- final fc: out = x @ Wf + bfp ----------------
__global__ __launch_bounds__(256) void gnn_fc(const float* __restrict__ x,
    const float* __restrict__ Wf, const float* __restrict__ bfp,
    float* __restrict__ out, int N) {
  int wave = threadIdx.x >> 6, lane = threadIdx.x & 63;
  int wid = blockIdx.x * 4 + wave, nw = gridDim.x * 4;
  int k0 = lane * 2;
  float w00 = Wf[k0 * 3 + 0], w01 = Wf[k0 * 3 + 1], w02 = Wf[k0 * 3 + 2];
  float w10 = Wf[k0 * 3 + 3], w11 = Wf[k0 * 3 + 4], w12 = Wf[k0 * 3 + 5];
  float bf0 = bfp[0], bf1 = bfp[1], bf2 = bfp[2];
  for (int v = wid; v < N; v += nw) {
    f32x2 xx = *(const f32x2*)(x + (size_t)v * HDIM + k0);
    float d0 = xx.x * w00 + xx.y * w10;
    float d1 = xx.x * w01 + xx.y * w11;
    float d2 = xx.x * w02 + xx.y * w12;
#pragma unroll
    for (int s = 32; s; s >>= 1) {
      d0 += __shfl_xor(d0, s, 64);
      d1 += __shfl_xor(d1, s, 64);
      d2 += __shfl_xor(d2, s, 64);
    }
    if (lane == 0) {
      out[(size_t)v * 3 + 0] = d0 + bf0;
      out[(size_t)v * 3 + 1] = d1 + bf1;
      out[(size_t)v * 3 + 2] = d2 + bf2;
    }
  }
}

extern "C" void kernel_launch(void* const* d_in, const int* in_sizes, int n_in,
                              void* d_out, int out_size, void* d_ws, size_t ws_size,
                              hipStream_t stream) {
  const float* x_in = (const float*)d_in[0];
  const int*   ei   = (const int*)d_in[1];
  const float* W1   = (const float*)d_in[2];
  const float* b1   = (const float*)d_in[3];
  const float* W2   = (const float*)d_in[4];
  const float* b2   = (const float*)d_in[5];
  const float* Wf   = (const float*)d_in[6];
  const float* bfv  = (const float*)d_in[7];
  float* outp = (float*)d_out;
  int N = in_sizes[0] / HDIM;
  int E = in_sizes[1] / 2;
  int S = E + N;

  char* ws = (char*)d_ws;
  size_t o = 0;
  auto alloc = [&](size_t bytes) -> char* {
    char* p = ws + o;
    o += (bytes + 255) & ~(size_t)255;
    return p;
  };
  int*   deg    = (int*)alloc((size_t)N * 4);
  int*   offs   = (int*)alloc(((size_t)N + 1) * 4);
  int*   cursor = (int*)alloc((size_t)N * 4);
  int*   colsrc = (int*)alloc((size_t)S * 4);
  int*   nodeof = (int*)alloc((size_t)S * 4);
  int*   bsum   = (int*)alloc(256 * 4);
  int*   boffs  = (int*)alloc(256 * 4);
  float* cbias  = (float*)alloc((size_t)LAYERS * 256 * 4);
  float* bfp    = (float*)alloc(4 * 4);
  float* P      = (float*)alloc((size_t)N * HDIM * 4);
  float* Q      = (float*)alloc((size_t)N * HDIM * 4);
  float* xbuf   = (float*)alloc((size_t)N * HDIM * 4);
  f16*   Wc     = (f16*)alloc((size_t)LAYERS * 65536 * 2);
  f16*   W2f    = (f16*)alloc((size_t)LAYERS * 32768 * 2);
  (void)ws_size; (void)n_in; (void)out_size;

  int nb = (N + 255) / 256;
  hipMemsetAsync(deg, 0, (size_t)N * 4, stream);
  gnn_hist<<<(E + 255) / 256, 256, 0, stream>>>(ei, deg, E);
  gnn_bsum<<<nb, 256, 0, stream>>>(deg, bsum, N);
  gnn_bscan<<<1, 256, 0, stream>>>(bsum, boffs, offs, nb, N);
  gnn_scan_fin<<<nb, 256, 0, stream>>>(deg, boffs, offs, cursor, colsrc, nodeof, N);
  gnn_scatter<<<(E + 255) / 256, 256, 0, stream>>>(ei, cursor, colsrc, E);
  gnn_biasprep<<<LAYERS + 1, 256, 0, stream>>>(W1, b1, b2, Wf, bfv, cbias, bfp);
  gnn_wprep1<<<(LAYERS * 128 * 256 + 255) / 256, 256, 0, stream>>>(W1, Wc);
  gnn_wprep2<<<(LAYERS * 128 * 128 + 255) / 256, 256, 0, stream>>>(W2, W2f);

  // slots per block: ~S/1024, rounded up to a multiple of TS(32)
  int spb = ((((S + 1023) / 1024) + TS - 1) / TS) * TS;
  int NB = (S + spb - 1) / spb;
  const float* xc = x_in;
  for (int l = 0; l < LAYERS; l++) {
    gnn_pq<<<(N + 63) / 64, 256, 0, stream>>>(xc, Wc + (size_t)l * 65536, cbias + l * 256,
                                              P, Q, N, offs, spb, xbuf);
    gnn_edge6<<<NB, 256, 0, stream>>>(P, Q, offs, colsrc, nodeof, W2f + (size_t)l * 32768,
                                      xbuf, S, spb);
    xc = xbuf;
  }
  gnn_fc<<<256, 256, 0, stream>>>(xc, Wf, bfp, outp, N);
}